// Round 5
// baseline (1995.582 us; speedup 1.0000x reference)
//
#include <hip/hip_runtime.h>
#include <stdint.h>

#define BB 8
#define CC 256
#define JJ 16
#define LL 256
#define NPIX 32768            // B*J*L
#define NEL (BB*CC*JJ*LL)     // 8388608
#define NBC 8192
#define NTOT 43296            // 32+256+2048+8192+32768

typedef unsigned short u16;
typedef short short8 __attribute__((ext_vector_type(8)));
typedef float floatx4 __attribute__((ext_vector_type(4)));

__device__ __forceinline__ uint32_t ord_f32(float f) {
  uint32_t u = __float_as_uint(f);
  return (u & 0x80000000u) ? ~u : (u | 0x80000000u);
}

__device__ __forceinline__ float cubw(float x) {
  const float a = -0.75f;
  float ax = fabsf(x);
  if (ax <= 1.f) return ((a + 2.f) * ax - (a + 3.f)) * ax * ax + 1.f;
  if (ax < 2.f)  return a * (ax * ((ax - 5.f) * ax + 8.f) - 4.f);
  return 0.f;
}

__device__ __forceinline__ u16 bf16h(float x) {
  uint32_t u = __float_as_uint(x);
  return (u16)((u + 0x7FFFu + ((u >> 16) & 1u)) >> 16);   // RNE
}
__device__ __forceinline__ float bf16f(u16 h) {
  return __uint_as_float(((uint32_t)h) << 16);
}

// ---------------------------------------------------------------- init small buffers
__global__ void k_init(unsigned long long* __restrict__ bkey,
                       uint32_t* __restrict__ counts, float* __restrict__ lacc) {
  int i = blockIdx.x * 256 + threadIdx.x;
  int stride = gridDim.x * 256;
  for (int x = i; x < NTOT; x += stride) bkey[x] = 0xFFFFFFFFFFFFFFFFull;
  for (int x = i; x < NBC; x += stride) counts[x] = 0u;
  if (i < 8) lacc[i] = 0.f;
}

// ---------------------------------------------------------------- f [B,C,J,L] -> pm [p][c]
__global__ void k_f2pm(const float* __restrict__ f, float* __restrict__ pm) {
  __shared__ float t[64][65];
  int tid = threadIdx.x;
  int px0 = blockIdx.x * 64, c0 = blockIdx.y * 64;
  int b = px0 >> 12, y = (px0 >> 8) & 15, x0 = px0 & 255;
#pragma unroll
  for (int it = 0; it < 4; ++it) {
    int slot = it * 256 + tid;
    int c = slot >> 4, q = (slot & 15) * 4;
    float4 v = *(const float4*)(f + (((size_t)(b * 256 + c0 + c)) * 16 + y) * 256 + x0 + q);
    t[c][q] = v.x; t[c][q + 1] = v.y; t[c][q + 2] = v.z; t[c][q + 3] = v.w;
  }
  __syncthreads();
#pragma unroll
  for (int it = 0; it < 4; ++it) {
    int slot = it * 256 + tid;
    int i = slot >> 4, q = (slot & 15) * 4;
    float4 v;
    v.x = t[q + 0][i]; v.y = t[q + 1][i]; v.z = t[q + 2][i]; v.w = t[q + 3][i];
    *(float4*)(pm + (size_t)(px0 + i) * 256 + c0 + q) = v;
  }
}

// ---------------------------------------------------------------- out = f - pm (transpose back)
__global__ void k_out(const float* __restrict__ f, const float* __restrict__ pm,
                      float* __restrict__ out) {
  __shared__ float t[64][65];
  int tid = threadIdx.x;
  int px0 = blockIdx.x * 64, c0 = blockIdx.y * 64;
  int b = px0 >> 12, y = (px0 >> 8) & 15, x0 = px0 & 255;
#pragma unroll
  for (int it = 0; it < 4; ++it) {
    int slot = it * 256 + tid;
    int i = slot >> 4, q = (slot & 15) * 4;
    float4 v = *(const float4*)(pm + (size_t)(px0 + i) * 256 + c0 + q);
    t[q + 0][i] = v.x; t[q + 1][i] = v.y; t[q + 2][i] = v.z; t[q + 3][i] = v.w;
  }
  __syncthreads();
#pragma unroll
  for (int it = 0; it < 4; ++it) {
    int slot = it * 256 + tid;
    int c = slot >> 4, q = (slot & 15) * 4;
    size_t g = (((size_t)(b * 256 + c0 + c)) * 16 + y) * 256 + x0 + q;
    float4 fv = *(const float4*)(f + g);
    float4 o;
    o.x = fv.x - t[c][q + 0]; o.y = fv.y - t[c][q + 1];
    o.z = fv.z - t[c][q + 2]; o.w = fv.w - t[c][q + 3];
    *(float4*)(out + g) = o;
  }
}

// ---------------------------------------------------------------- cb_sq
__global__ void k_cbsq(const float* __restrict__ cb, float* __restrict__ cbsq) {
  int k = blockIdx.x * blockDim.x + threadIdx.x;
  if (k >= NBC) return;
  const float4* row = (const float4*)(cb + (size_t)k * CC);
  float s = 0.f;
  for (int i = 0; i < CC / 4; ++i) {
    float4 v = row[i];
    s += v.x * v.x + v.y * v.y + v.z * v.z + v.w * v.w;
  }
  cbsq[k] = s;
}

// ---------------------------------------------------------------- fp32 -> split bf16 (codebook prep)
__global__ void k_split(const float* __restrict__ src, u16* __restrict__ hi,
                        u16* __restrict__ lo, int n) {
  int i = (blockIdx.x * 256 + threadIdx.x) * 4;
  if (i >= n) return;
  float4 v = *(const float4*)(src + i);
  ushort4 h, l;
  h.x = bf16h(v.x); l.x = bf16h(v.x - bf16f(h.x));
  h.y = bf16h(v.y); l.y = bf16h(v.y - bf16f(h.y));
  h.z = bf16h(v.z); l.z = bf16h(v.z - bf16f(h.z));
  h.w = bf16h(v.w); l.w = bf16h(v.w - bf16f(h.w));
  *(ushort4*)(hi + i) = h;
  *(ushort4*)(lo + i) = l;
}

// ---------------------------------------------------------------- weight split/transpose prep
__global__ void k_wprep(const float* __restrict__ pw, u16* __restrict__ Whi,
                        u16* __restrict__ Wlo) {
  int bx = blockIdx.x;          // (phi*9+s)*256 + co
  int co = bx & 255;
  int ps = bx >> 8;             // phi*9+s
  int phi = ps / 9, s = ps % 9;
  int ci = threadIdx.x;
  float v = pw[(((size_t)(phi * 256 + co)) * 256 + ci) * 9 + s];
  u16 h = bf16h(v);
  Whi[(size_t)bx * 256 + ci] = h;
  Wlo[(size_t)bx * 256 + ci] = bf16h(v - bf16f(h));
}

// ---------------------------------------------------------------- pooling (pixel-major), 2-phase
__global__ void k_poolpart(const float* __restrict__ pm, float* __restrict__ part,
                           int sn, int tn, int pj, int wl, int K, int ppk) {
  int n = blockIdx.x, kk = blockIdx.y, c = threadIdx.x;
  int b = n / (sn * tn);
  int s = (n / tn) % sn;
  int t = n % tn;
  float acc = 0.f;
  for (int q = kk * ppk; q < (kk + 1) * ppk; ++q) {
    int yy = s * pj + q / wl;
    int xx = t * wl + q % wl;
    size_t p = (size_t)b * 4096 + (size_t)yy * 256 + xx;
    acc += pm[p * 256 + c];
  }
  part[((size_t)n * K + kk) * 256 + c] = acc;
}

__global__ void k_poolfin(const float* __restrict__ part, float* __restrict__ rows,
                          int K, float inv) {
  int n = blockIdx.x, c = threadIdx.x;
  float s = 0.f;
  for (int kk = 0; kk < K; ++kk) s += part[((size_t)n * K + kk) * 256 + c];
  rows[(size_t)n * 256 + c] = s * inv;
}

// ---------------------------------------------------------------- MFMA codebook argmin v5
// 256-thread block, 4 waves x 32 resident queries (fp32 loaded, split in-reg).
// Code tiles of 32 stored FRAGMENT-MAJOR in LDS: chunk lin=(kc*2+nt)*64+quad*16+lm
// at offset lin*16B -> MFMA B-read is ds_read_b128 at base+lane*16 (contiguous,
// conflict-free). Software double-buffer, one barrier per tile.
#define MS_QB 128
__global__ __launch_bounds__(256, 2) void k_msearch(
    const float* __restrict__ Q,
    const u16* __restrict__ CBhi, const u16* __restrict__ CBlo,
    const float* __restrict__ cbsq, unsigned long long* __restrict__ bkey,
    int nQ, int tilesPerBlock) {
  __shared__ __align__(16) u16 Bh[2][32 * 256];
  __shared__ __align__(16) u16 Bl[2][32 * 256];
  __shared__ float sq[2][32];
  int tid = threadIdx.x;
  int wid = tid >> 6, lane = tid & 63;
  int lm = lane & 15, quad = lane >> 4;
  int qw = blockIdx.x * MS_QB + wid * 32;
  int t0 = blockIdx.y * tilesPerBlock;

  // staging map: thread stages chunks lin = tid + c*256
  int goff[4];
#pragma unroll
  for (int c = 0; c < 4; ++c) {
    int lin = tid + c * 256;
    int l4 = lin & 15, q4 = (lin >> 4) & 3, nt = (lin >> 6) & 1, kc = lin >> 7;
    goff[c] = (nt * 16 + l4) * 256 + kc * 32 + q4 * 8;
  }

  // resident Q A-frags (fp32 -> split bf16 in-reg)
  short8 qh[2][8], ql[2][8];
#pragma unroll
  for (int mt = 0; mt < 2; ++mt)
#pragma unroll
    for (int kc = 0; kc < 8; ++kc) {
      const float* qp = Q + (size_t)(qw + mt * 16 + lm) * 256 + kc * 32 + quad * 8;
      float4 a = *(const float4*)qp;
      float4 b = *(const float4*)(qp + 4);
      float v[8] = {a.x, a.y, a.z, a.w, b.x, b.y, b.z, b.w};
      short8 h, l;
#pragma unroll
      for (int e = 0; e < 8; ++e) {
        u16 hh = bf16h(v[e]);
        h[e] = (short)hh;
        l[e] = (short)bf16h(v[e] - bf16f(hh));
      }
      qh[mt][kc] = h;
      ql[mt][kc] = l;
    }

  unsigned long long rk[2][4];
#pragma unroll
  for (int mt = 0; mt < 2; ++mt)
#pragma unroll
    for (int r = 0; r < 4; ++r) rk[mt][r] = 0xFFFFFFFFFFFFFFFFull;

  // prologue: stage tile 0 into buffer 0
  {
    size_t n0b = (size_t)t0 * 32 * 256;
    float sv = (tid < 32) ? cbsq[t0 * 32 + tid] : 0.f;
    uint4 rh[4], rl[4];
#pragma unroll
    for (int c = 0; c < 4; ++c) {
      rh[c] = *(const uint4*)(CBhi + n0b + goff[c]);
      rl[c] = *(const uint4*)(CBlo + n0b + goff[c]);
    }
#pragma unroll
    for (int c = 0; c < 4; ++c) {
      int lin = tid + c * 256;
      *(uint4*)&Bh[0][lin * 8] = rh[c];
      *(uint4*)&Bl[0][lin * 8] = rl[c];
    }
    if (tid < 32) sq[0][tid] = sv;
  }
  __syncthreads();

  for (int t = 0; t < tilesPerBlock; ++t) {
    int p = t & 1;
    bool pre = (t + 1 < tilesPerBlock);
    uint4 rh[4], rl[4];
    float sv = 0.f;
    if (pre) {
      int n1 = (t0 + t + 1) * 32;
      size_t n1b = (size_t)n1 * 256;
      if (tid < 32) sv = cbsq[n1 + tid];
#pragma unroll
      for (int c = 0; c < 4; ++c) {
        rh[c] = *(const uint4*)(CBhi + n1b + goff[c]);
        rl[c] = *(const uint4*)(CBlo + n1b + goff[c]);
      }
    }
    int n0 = (t0 + t) * 32;
#pragma unroll
    for (int nt = 0; nt < 2; ++nt) {
      floatx4 acc0 = {0.f, 0.f, 0.f, 0.f}, acc1 = {0.f, 0.f, 0.f, 0.f};
#pragma unroll
      for (int kc = 0; kc < 8; ++kc) {
        int lb = ((kc * 2 + nt) * 64 + lane) * 8;
        short8 bh = *(const short8*)&Bh[p][lb];
        short8 bl = *(const short8*)&Bl[p][lb];
        acc0 = __builtin_amdgcn_mfma_f32_16x16x32_bf16(qh[0][kc], bh, acc0, 0, 0, 0);
        acc0 = __builtin_amdgcn_mfma_f32_16x16x32_bf16(qh[0][kc], bl, acc0, 0, 0, 0);
        acc0 = __builtin_amdgcn_mfma_f32_16x16x32_bf16(ql[0][kc], bh, acc0, 0, 0, 0);
        acc1 = __builtin_amdgcn_mfma_f32_16x16x32_bf16(qh[1][kc], bh, acc1, 0, 0, 0);
        acc1 = __builtin_amdgcn_mfma_f32_16x16x32_bf16(qh[1][kc], bl, acc1, 0, 0, 0);
        acc1 = __builtin_amdgcn_mfma_f32_16x16x32_bf16(ql[1][kc], bh, acc1, 0, 0, 0);
      }
      uint32_t code = (uint32_t)(n0 + nt * 16 + lm);
      float csq = sq[p][nt * 16 + lm];
#pragma unroll
      for (int r = 0; r < 4; ++r) {
        float d0 = csq - 2.f * acc0[r];
        float d1 = csq - 2.f * acc1[r];
        unsigned long long k0 = ((unsigned long long)ord_f32(d0) << 32) | code;
        unsigned long long k1 = ((unsigned long long)ord_f32(d1) << 32) | code;
        if (k0 < rk[0][r]) rk[0][r] = k0;
        if (k1 < rk[1][r]) rk[1][r] = k1;
      }
    }
    if (pre) {
#pragma unroll
      for (int c = 0; c < 4; ++c) {
        int lin = tid + c * 256;
        *(uint4*)&Bh[p ^ 1][lin * 8] = rh[c];
        *(uint4*)&Bl[p ^ 1][lin * 8] = rl[c];
      }
      if (tid < 32) sq[p ^ 1][tid] = sv;
      __syncthreads();
    }
  }

#pragma unroll
  for (int mt = 0; mt < 2; ++mt)
#pragma unroll
    for (int r = 0; r < 4; ++r) {
      unsigned long long k = rk[mt][r];
#pragma unroll
      for (int off = 1; off <= 8; off <<= 1) {
        uint32_t lo = (uint32_t)k, hi = (uint32_t)(k >> 32);
        uint32_t olo = __shfl_xor(lo, off, 64);
        uint32_t ohi = __shfl_xor(hi, off, 64);
        unsigned long long ok = ((unsigned long long)ohi << 32) | olo;
        if (ok < k) k = ok;
      }
      if (lm == 0) {
        int q = qw + mt * 16 + quad * 4 + r;
        if (q < nQ) atomicMin(&bkey[q], k);
      }
    }
}

// ---------------------------------------------------------------- gather + bicubic up -> split bf16 H
__global__ void k_upgather(const unsigned long long* __restrict__ bkey,
                           const float* __restrict__ cb,
                           u16* __restrict__ Hhi, u16* __restrict__ Hlo,
                           int sn, int tn, int last) {
  __shared__ int sidx[8][16];
  __shared__ float swgt[8][16];
  int tid = threadIdx.x;
  int p0 = blockIdx.x * 8;
  if (!last) {
    if (tid < 128) {
      int pp = tid >> 4, tap = tid & 15;
      int aa = tap >> 2, ee = tap & 3;
      int p = p0 + pp;
      int b = p >> 12, y = (p >> 8) & 15, x = p & 255;
      float cj = (y + 0.5f) * ((float)sn / 16.f) - 0.5f;
      float fj = floorf(cj); float tj = cj - fj; int ij = (int)fj;
      float wj = cubw(tj - (float)(aa - 1));
      int xj = min(max(ij + aa - 1, 0), sn - 1);
      float cl = (x + 0.5f) * ((float)tn / 256.f) - 0.5f;
      float fl = floorf(cl); float tl = cl - fl; int il = (int)fl;
      float wle = cubw(tl - (float)(ee - 1));
      int xl = min(max(il + ee - 1, 0), tn - 1);
      int n = (b * sn + xj) * tn + xl;
      sidx[pp][tap] = (int)((uint32_t)bkey[n] & (NBC - 1));
      swgt[pp][tap] = wj * wle;
    }
  } else {
    if (tid < 8) sidx[tid][0] = (int)((uint32_t)bkey[p0 + tid] & (NBC - 1));
  }
  __syncthreads();
  int c = tid;
  for (int pp = 0; pp < 8; ++pp) {
    float val;
    if (last) {
      val = cb[(size_t)sidx[pp][0] * 256 + c];
    } else {
      val = 0.f;
#pragma unroll
      for (int tap = 0; tap < 16; ++tap)
        val += swgt[pp][tap] * cb[(size_t)sidx[pp][tap] * 256 + c];
    }
    u16 h = bf16h(val);
    u16 l = bf16h(val - bf16f(h));
    size_t g = (size_t)(p0 + pp) * 256 + c;
    Hhi[g] = h;
    Hlo[g] = l;
  }
}

// ---------------------------------------------------------------- conv3x3 as split-bf16 MFMA implicit GEMM
__global__ __launch_bounds__(256) void k_conv(
    const u16* __restrict__ Hhi, const u16* __restrict__ Hlo,
    const u16* __restrict__ Wh, const u16* __restrict__ Wl,
    const float* __restrict__ bias, float* __restrict__ pm,
    float* __restrict__ lacc, int si) {
  __shared__ __align__(16) u16 Ah[128 * 40];
  __shared__ __align__(16) u16 Al[128 * 40];
  __shared__ __align__(16) u16 Bh[128 * 40];
  __shared__ __align__(16) u16 Bl[128 * 40];
  __shared__ float redl[4];
  int tid = threadIdx.x;
  int mt = blockIdx.x >> 1, nt = blockIdx.x & 1;
  int px0 = mt * 128;
  int b4096 = px0 & ~4095;
  int y = (px0 >> 8) & 15;
  int x0 = px0 & 255;
  int co0 = nt * 128;
  int wid = tid >> 6, lane = tid & 63;
  int wm = wid & 1, wn = wid >> 1;
  int lm = lane & 15, quad = lane >> 4, k0 = quad * 8;

  floatx4 acc[4][4];
#pragma unroll
  for (int i = 0; i < 4; ++i)
#pragma unroll
    for (int j = 0; j < 4; ++j) acc[i][j] = (floatx4){0.f, 0.f, 0.f, 0.f};

  for (int s = 0; s < 9; ++s) {
    int dy = s / 3 - 1, dx = s % 3 - 1;
    int ys = y + dy;
    if (ys < 0 || ys > 15) continue;       // wave-uniform skip
    const u16* wbh = Wh + (size_t)s * 65536;
    const u16* wbl = Wl + (size_t)s * 65536;
    for (int ci0 = 0; ci0 < 256; ci0 += 32) {
      __syncthreads();
#pragma unroll
      for (int it = 0; it < 2; ++it) {
        int slot = tid + it * 256;
        int pxl = slot >> 2, ch = (slot & 3) * 8;
        int xs = x0 + pxl + dx;
        uint4 vh = {0, 0, 0, 0}, vl = {0, 0, 0, 0};
        if (xs >= 0 && xs < 256) {
          size_t g = ((size_t)(b4096 + ys * 256 + xs)) * 256 + ci0 + ch;
          vh = *(const uint4*)(Hhi + g);
          vl = *(const uint4*)(Hlo + g);
        }
        *(uint4*)&Ah[pxl * 40 + ch] = vh;
        *(uint4*)&Al[pxl * 40 + ch] = vl;
        size_t gw = (size_t)(co0 + pxl) * 256 + ci0 + ch;
        *(uint4*)&Bh[pxl * 40 + ch] = *(const uint4*)(wbh + gw);
        *(uint4*)&Bl[pxl * 40 + ch] = *(const uint4*)(wbl + gw);
      }
      __syncthreads();
      short8 ah[4], al[4], bh[4], bl[4];
#pragma unroll
      for (int mi = 0; mi < 4; ++mi) {
        int r = wm * 64 + mi * 16 + lm;
        ah[mi] = *(const short8*)&Ah[r * 40 + k0];
        al[mi] = *(const short8*)&Al[r * 40 + k0];
      }
#pragma unroll
      for (int ni = 0; ni < 4; ++ni) {
        int r = wn * 64 + ni * 16 + lm;
        bh[ni] = *(const short8*)&Bh[r * 40 + k0];
        bl[ni] = *(const short8*)&Bl[r * 40 + k0];
      }
#pragma unroll
      for (int mi = 0; mi < 4; ++mi)
#pragma unroll
        for (int ni = 0; ni < 4; ++ni) {
          acc[mi][ni] = __builtin_amdgcn_mfma_f32_16x16x32_bf16(ah[mi], bh[ni], acc[mi][ni], 0, 0, 0);
          acc[mi][ni] = __builtin_amdgcn_mfma_f32_16x16x32_bf16(ah[mi], bl[ni], acc[mi][ni], 0, 0, 0);
          acc[mi][ni] = __builtin_amdgcn_mfma_f32_16x16x32_bf16(al[mi], bh[ni], acc[mi][ni], 0, 0, 0);
        }
    }
  }

  float lsum = 0.f;
#pragma unroll
  for (int mi = 0; mi < 4; ++mi) {
#pragma unroll
    for (int ni = 0; ni < 4; ++ni) {
      int co = co0 + wn * 64 + ni * 16 + lm;
      float bv = bias[co];
#pragma unroll
      for (int r = 0; r < 4; ++r) {
        int px = px0 + wm * 64 + mi * 16 + quad * 4 + r;
        size_t g = (size_t)px * 256 + co;
        float h = bf16f(Hhi[g]) + bf16f(Hlo[g]);
        float o = 0.5f * h + 0.5f * (acc[mi][ni][r] + bv);
        float fr = pm[g] - o;
        pm[g] = fr;
        lsum += fr * fr;
      }
    }
  }
  for (int off = 32; off; off >>= 1) lsum += __shfl_xor(lsum, off, 64);
  if (lane == 0) redl[wid] = lsum;
  __syncthreads();
  if (tid == 0) atomicAdd(&lacc[si], redl[0] + redl[1] + redl[2] + redl[3]);
}

// ---------------------------------------------------------------- histogram
__global__ void k_hist(const unsigned long long* __restrict__ bkey,
                       uint32_t* __restrict__ counts) {
  int i = blockIdx.x * 256 + threadIdx.x;
  if (i < NTOT) atomicAdd(&counts[(uint32_t)bkey[i] & (NBC - 1)], 1u);
}

// ---------------------------------------------------------------- loss + perplexity scalars
__global__ void k_scalars(const uint32_t* __restrict__ counts,
                          const float* __restrict__ lacc,
                          float* __restrict__ out) {
  __shared__ float red[4];
  int tid = threadIdx.x;
  float s = 0.f;
  for (int i = tid; i < NBC; i += 256) {
    float p = (float)counts[i] * (1.0f / (float)NTOT);
    s += p * logf(p + 1e-7f);
  }
  for (int off = 32; off; off >>= 1) s += __shfl_xor(s, off, 64);
  if ((tid & 63) == 0) red[tid >> 6] = s;
  __syncthreads();
  if (tid == 0) {
    float ent = red[0] + red[1] + red[2] + red[3];
    out[NEL + 1] = expf(-ent);
    float l = 0.f;
    for (int i = 0; i < 5; ++i) l += lacc[i];
    out[NEL] = l * (1.0f / (float)NEL / 5.0f);
  }
}

extern "C" void kernel_launch(void* const* d_in, const int* in_sizes, int n_in,
                              void* d_out, int out_size, void* d_ws, size_t ws_size,
                              hipStream_t stream) {
  const float* f  = (const float*)d_in[0];
  const float* cb = (const float*)d_in[1];
  const float* pw = (const float*)d_in[2];
  const float* pb = (const float*)d_in[3];
  float* out = (float*)d_out;

  char* ws = (char*)d_ws;
  size_t off = 0;
  auto alloc = [&](size_t bytes) {
    void* p = ws + off;
    off += (bytes + 255) & ~(size_t)255;
    return p;
  };
  float* pm    = (float*)alloc((size_t)NEL * 4);            // f_rest, pixel-major [p][c]
  u16*   Hhi   = (u16*)alloc((size_t)NEL * 2);
  u16*   Hlo   = (u16*)alloc((size_t)NEL * 2);
  float* rows  = (float*)alloc((size_t)8192 * 256 * 4);
  float* part  = (float*)alloc((size_t)8192 * 256 * 4);
  u16*   Whi   = (u16*)alloc((size_t)4 * 9 * 65536 * 2);
  u16*   Wlo   = (u16*)alloc((size_t)4 * 9 * 65536 * 2);
  u16*   CBhi  = (u16*)alloc((size_t)NBC * 256 * 2);
  u16*   CBlo  = (u16*)alloc((size_t)NBC * 256 * 2);
  float* cbsq  = (float*)alloc((size_t)NBC * 4);
  unsigned long long* bkey = (unsigned long long*)alloc((size_t)NTOT * 8);
  uint32_t* counts = (uint32_t*)alloc((size_t)NBC * 4);
  float* lacc = (float*)alloc(8 * 4);

  k_init<<<256, 256, 0, stream>>>(bkey, counts, lacc);
  k_f2pm<<<dim3(NPIX / 64, 4), 256, 0, stream>>>(f, pm);
  k_cbsq<<<NBC / 256, 256, 0, stream>>>(cb, cbsq);
  k_split<<<(NBC * 256) / 1024, 256, 0, stream>>>(cb, CBhi, CBlo, NBC * 256);
  k_wprep<<<4 * 9 * 256, 256, 0, stream>>>(pw, Whi, Wlo);

  const int SNs[5]   = {1, 2, 4, 8, 16};
  const int TNs[5]   = {4, 16, 64, 128, 256};
  const int PHI[5]   = {0, 1, 1, 2, 3};
  const int KCH[5]   = {256, 128, 32, 8, 2};  // code-chunk grid dim (256 tiles of 32)
  const int Ks[5]    = {16, 8, 2, 1, 1};
  int offs = 0;
  for (int si = 0; si < 5; ++si) {
    int sn = SNs[si], tn = TNs[si];
    int N = BB * sn * tn;
    int pj = JJ / sn, wl = LL / tn;
    unsigned long long* bk = bkey + offs;
    const float* qsrc;
    if (si < 4) {
      int K = Ks[si], npx = pj * wl;
      k_poolpart<<<dim3(N, K), 256, 0, stream>>>(pm, part, sn, tn, pj, wl, K, npx / K);
      k_poolfin<<<N, 256, 0, stream>>>(part, rows, K, 1.0f / (float)npx);
      qsrc = rows;
    } else {
      qsrc = pm;   // pixel-major residual IS the query matrix (fp32)
    }
    int qtiles = (N + MS_QB - 1) / MS_QB;
    int tpb = (NBC / 32) / KCH[si];
    dim3 g(qtiles, KCH[si]);
    k_msearch<<<g, 256, 0, stream>>>(qsrc, CBhi, CBlo, cbsq, bk, N, tpb);
    k_upgather<<<NPIX / 8, 256, 0, stream>>>(bk, cb, Hhi, Hlo, sn, tn, si == 4);
    k_conv<<<512, 256, 0, stream>>>(Hhi, Hlo,
                                    Whi + (size_t)PHI[si] * 9 * 65536,
                                    Wlo + (size_t)PHI[si] * 9 * 65536,
                                    pb + (size_t)PHI[si] * 256, pm, lacc, si);
    offs += N;
  }
  k_hist<<<(NTOT + 255) / 256, 256, 0, stream>>>(bkey, counts);
  k_out<<<dim3(NPIX / 64, 4), 256, 0, stream>>>(f, pm, out);
  k_scalars<<<1, 256, 0, stream>>>(counts, lacc, out);
}

// Round 6
// 1564.644 us; speedup vs baseline: 1.2754x; 1.2754x over previous
//
#include <hip/hip_runtime.h>
#include <stdint.h>

#define BB 8
#define CC 256
#define JJ 16
#define LL 256
#define NPIX 32768            // B*J*L
#define NEL (BB*CC*JJ*LL)     // 8388608
#define NBC 8192
#define NTOT 43296            // 32+256+2048+8192+32768

typedef unsigned short u16;
typedef short short8 __attribute__((ext_vector_type(8)));
typedef float floatx4 __attribute__((ext_vector_type(4)));

__device__ __forceinline__ uint32_t ord_f32(float f) {
  uint32_t u = __float_as_uint(f);
  return (u & 0x80000000u) ? ~u : (u | 0x80000000u);
}

__device__ __forceinline__ float cubw(float x) {
  const float a = -0.75f;
  float ax = fabsf(x);
  if (ax <= 1.f) return ((a + 2.f) * ax - (a + 3.f)) * ax * ax + 1.f;
  if (ax < 2.f)  return a * (ax * ((ax - 5.f) * ax + 8.f) - 4.f);
  return 0.f;
}

__device__ __forceinline__ u16 bf16h(float x) {
  uint32_t u = __float_as_uint(x);
  return (u16)((u + 0x7FFFu + ((u >> 16) & 1u)) >> 16);   // RNE
}
__device__ __forceinline__ float bf16f(u16 h) {
  return __uint_as_float(((uint32_t)h) << 16);
}

// async global->LDS, 16B per lane; LDS dst is wave-uniform base + lane*16.
__device__ __forceinline__ void gload_lds16(const void* g, void* l) {
  __builtin_amdgcn_global_load_lds(
      (__attribute__((address_space(1))) void*)g,
      (__attribute__((address_space(3))) void*)(uint32_t)(uintptr_t)l,
      16, 0, 0);
}

// ---------------------------------------------------------------- init small buffers
__global__ void k_init(unsigned long long* __restrict__ bkey,
                       uint32_t* __restrict__ counts, float* __restrict__ lacc) {
  int i = blockIdx.x * 256 + threadIdx.x;
  int stride = gridDim.x * 256;
  for (int x = i; x < NTOT; x += stride) bkey[x] = 0xFFFFFFFFFFFFFFFFull;
  for (int x = i; x < NBC; x += stride) counts[x] = 0u;
  if (i < 8) lacc[i] = 0.f;
}

// ---------------------------------------------------------------- f [B,C,J,L] -> pm [p][c]
__global__ void k_f2pm(const float* __restrict__ f, float* __restrict__ pm) {
  __shared__ float t[64][65];
  int tid = threadIdx.x;
  int px0 = blockIdx.x * 64, c0 = blockIdx.y * 64;
  int b = px0 >> 12, y = (px0 >> 8) & 15, x0 = px0 & 255;
#pragma unroll
  for (int it = 0; it < 4; ++it) {
    int slot = it * 256 + tid;
    int c = slot >> 4, q = (slot & 15) * 4;
    float4 v = *(const float4*)(f + (((size_t)(b * 256 + c0 + c)) * 16 + y) * 256 + x0 + q);
    t[c][q] = v.x; t[c][q + 1] = v.y; t[c][q + 2] = v.z; t[c][q + 3] = v.w;
  }
  __syncthreads();
#pragma unroll
  for (int it = 0; it < 4; ++it) {
    int slot = it * 256 + tid;
    int i = slot >> 4, q = (slot & 15) * 4;
    float4 v;
    v.x = t[q + 0][i]; v.y = t[q + 1][i]; v.z = t[q + 2][i]; v.w = t[q + 3][i];
    *(float4*)(pm + (size_t)(px0 + i) * 256 + c0 + q) = v;
  }
}

// ---------------------------------------------------------------- out = f - pm (transpose back)
__global__ void k_out(const float* __restrict__ f, const float* __restrict__ pm,
                      float* __restrict__ out) {
  __shared__ float t[64][65];
  int tid = threadIdx.x;
  int px0 = blockIdx.x * 64, c0 = blockIdx.y * 64;
  int b = px0 >> 12, y = (px0 >> 8) & 15, x0 = px0 & 255;
#pragma unroll
  for (int it = 0; it < 4; ++it) {
    int slot = it * 256 + tid;
    int i = slot >> 4, q = (slot & 15) * 4;
    float4 v = *(const float4*)(pm + (size_t)(px0 + i) * 256 + c0 + q);
    t[q + 0][i] = v.x; t[q + 1][i] = v.y; t[q + 2][i] = v.z; t[q + 3][i] = v.w;
  }
  __syncthreads();
#pragma unroll
  for (int it = 0; it < 4; ++it) {
    int slot = it * 256 + tid;
    int c = slot >> 4, q = (slot & 15) * 4;
    size_t g = (((size_t)(b * 256 + c0 + c)) * 16 + y) * 256 + x0 + q;
    float4 fv = *(const float4*)(f + g);
    float4 o;
    o.x = fv.x - t[c][q + 0]; o.y = fv.y - t[c][q + 1];
    o.z = fv.z - t[c][q + 2]; o.w = fv.w - t[c][q + 3];
    *(float4*)(out + g) = o;
  }
}

// ---------------------------------------------------------------- cb_sq
__global__ void k_cbsq(const float* __restrict__ cb, float* __restrict__ cbsq) {
  int k = blockIdx.x * blockDim.x + threadIdx.x;
  if (k >= NBC) return;
  const float4* row = (const float4*)(cb + (size_t)k * CC);
  float s = 0.f;
  for (int i = 0; i < CC / 4; ++i) {
    float4 v = row[i];
    s += v.x * v.x + v.y * v.y + v.z * v.z + v.w * v.w;
  }
  cbsq[k] = s;
}

// ---------------------------------------------------------------- codebook -> fragment-major split bf16
// Per 32-code tile: 1024 chunks of 16B. chunk lin = (kc*2+nt)*64 + quad*16 + lm holds
// cb[t*32 + nt*16 + lm][kc*32 + quad*8 .. +8]. Matches msearch's ds_read_b128 at
// base + lane*16 AND global_load_lds wave staging (both contiguous).
__global__ void k_cbprep(const float* __restrict__ cb, u16* __restrict__ fmh,
                         u16* __restrict__ fml) {
  int gid = blockIdx.x * 256 + threadIdx.x;   // tile*1024 + lin, total 262144
  int t = gid >> 10, lin = gid & 1023;
  int kcnt = lin >> 6;
  int kc = kcnt >> 1, nt = kcnt & 1;
  int lane = lin & 63;
  int lm = lane & 15, quad = lane >> 4;
  int code = t * 32 + nt * 16 + lm;
  int k = kc * 32 + quad * 8;
  const float* s = cb + (size_t)code * 256 + k;
  float4 a = *(const float4*)s;
  float4 b = *(const float4*)(s + 4);
  float v[8] = {a.x, a.y, a.z, a.w, b.x, b.y, b.z, b.w};
  ushort4 h0, h1, l0, l1;
  u16 hh[8], ll[8];
#pragma unroll
  for (int e = 0; e < 8; ++e) {
    hh[e] = bf16h(v[e]);
    ll[e] = bf16h(v[e] - bf16f(hh[e]));
  }
  h0 = make_ushort4(hh[0], hh[1], hh[2], hh[3]);
  h1 = make_ushort4(hh[4], hh[5], hh[6], hh[7]);
  l0 = make_ushort4(ll[0], ll[1], ll[2], ll[3]);
  l1 = make_ushort4(ll[4], ll[5], ll[6], ll[7]);
  *(ushort4*)(fmh + (size_t)gid * 8) = h0;
  *(ushort4*)(fmh + (size_t)gid * 8 + 4) = h1;
  *(ushort4*)(fml + (size_t)gid * 8) = l0;
  *(ushort4*)(fml + (size_t)gid * 8 + 4) = l1;
}

// ---------------------------------------------------------------- weight split/transpose prep
__global__ void k_wprep(const float* __restrict__ pw, u16* __restrict__ Whi,
                        u16* __restrict__ Wlo) {
  int bx = blockIdx.x;          // (phi*9+s)*256 + co
  int co = bx & 255;
  int ps = bx >> 8;             // phi*9+s
  int phi = ps / 9, s = ps % 9;
  int ci = threadIdx.x;
  float v = pw[(((size_t)(phi * 256 + co)) * 256 + ci) * 9 + s];
  u16 h = bf16h(v);
  Whi[(size_t)bx * 256 + ci] = h;
  Wlo[(size_t)bx * 256 + ci] = bf16h(v - bf16f(h));
}

// ---------------------------------------------------------------- pooling (pixel-major), 2-phase
__global__ void k_poolpart(const float* __restrict__ pm, float* __restrict__ part,
                           int sn, int tn, int pj, int wl, int K, int ppk) {
  int n = blockIdx.x, kk = blockIdx.y, c = threadIdx.x;
  int b = n / (sn * tn);
  int s = (n / tn) % sn;
  int t = n % tn;
  float acc = 0.f;
  for (int q = kk * ppk; q < (kk + 1) * ppk; ++q) {
    int yy = s * pj + q / wl;
    int xx = t * wl + q % wl;
    size_t p = (size_t)b * 4096 + (size_t)yy * 256 + xx;
    acc += pm[p * 256 + c];
  }
  part[((size_t)n * K + kk) * 256 + c] = acc;
}

__global__ void k_poolfin(const float* __restrict__ part, float* __restrict__ rows,
                          int K, float inv) {
  int n = blockIdx.x, c = threadIdx.x;
  float s = 0.f;
  for (int kk = 0; kk < K; ++kk) s += part[((size_t)n * K + kk) * 256 + c];
  rows[(size_t)n * 256 + c] = s * inv;
}

// ---------------------------------------------------------------- MFMA codebook argmin v6
// 256-thread block, 4 waves x 32 resident queries (fp32 loaded, split in-reg; no
// other long-lived staging registers -> no spill). Code tiles of 32 streamed via
// global_load_lds (width 16) from fragment-major CBfm into double-buffered LDS;
// one barrier per tile (drains vmcnt). MFMA B-read = ds_read_b128 at base+lane*16,
// conflict-free. 3-term split-bf16, bit-identical to R3/R4/R5 numerics.
#define MS_QB 128
__global__ __launch_bounds__(256, 2) void k_msearch(
    const float* __restrict__ Q,
    const u16* __restrict__ FH, const u16* __restrict__ FL,
    const float* __restrict__ cbsq, unsigned long long* __restrict__ bkey,
    int nQ, int tilesPerBlock) {
  __shared__ __align__(16) u16 Bh[2][8192];   // 16 KB per buffer
  __shared__ __align__(16) u16 Bl[2][8192];
  int tid = threadIdx.x;
  int wid = tid >> 6, lane = tid & 63;
  int lm = lane & 15, quad = lane >> 4;
  int qw = blockIdx.x * MS_QB + wid * 32;
  int t0 = blockIdx.y * tilesPerBlock;
  int blane = wid * 4096 + lane * 16;         // byte offset of this lane's chunk 0

  // resident Q A-frags (fp32 -> split bf16 in-reg)
  short8 qh[2][8], ql[2][8];
#pragma unroll
  for (int mt = 0; mt < 2; ++mt)
#pragma unroll
    for (int kc = 0; kc < 8; ++kc) {
      const float* qp = Q + (size_t)(qw + mt * 16 + lm) * 256 + kc * 32 + quad * 8;
      float4 a = *(const float4*)qp;
      float4 b = *(const float4*)(qp + 4);
      float v[8] = {a.x, a.y, a.z, a.w, b.x, b.y, b.z, b.w};
      short8 h, l;
#pragma unroll
      for (int e = 0; e < 8; ++e) {
        u16 hh = bf16h(v[e]);
        h[e] = (short)hh;
        l[e] = (short)bf16h(v[e] - bf16f(hh));
      }
      qh[mt][kc] = h;
      ql[mt][kc] = l;
    }

  unsigned long long rk[2][4];
#pragma unroll
  for (int mt = 0; mt < 2; ++mt)
#pragma unroll
    for (int r = 0; r < 4; ++r) rk[mt][r] = 0xFFFFFFFFFFFFFFFFull;

  // prologue: DMA tile t0 into buffer 0
  {
    const char* sh = (const char*)FH + (size_t)t0 * 16384;
    const char* sl = (const char*)FL + (size_t)t0 * 16384;
#pragma unroll
    for (int i = 0; i < 4; ++i) {
      gload_lds16(sh + blane + i * 1024, (char*)&Bh[0][0] + wid * 4096 + i * 1024);
      gload_lds16(sl + blane + i * 1024, (char*)&Bl[0][0] + wid * 4096 + i * 1024);
    }
  }
  __syncthreads();

  for (int t = 0; t < tilesPerBlock; ++t) {
    int p = t & 1;
    bool pre = (t + 1 < tilesPerBlock);
    if (pre) {   // issue next tile's DMA into the other buffer (no data registers)
      const char* sh = (const char*)FH + (size_t)(t0 + t + 1) * 16384;
      const char* sl = (const char*)FL + (size_t)(t0 + t + 1) * 16384;
#pragma unroll
      for (int i = 0; i < 4; ++i) {
        gload_lds16(sh + blane + i * 1024, (char*)&Bh[p ^ 1][0] + wid * 4096 + i * 1024);
        gload_lds16(sl + blane + i * 1024, (char*)&Bl[p ^ 1][0] + wid * 4096 + i * 1024);
      }
    }
    int n0 = (t0 + t) * 32;
    float csq0 = cbsq[n0 + lm];
    float csq1 = cbsq[n0 + 16 + lm];
#pragma unroll
    for (int nt = 0; nt < 2; ++nt) {
      floatx4 acc0 = {0.f, 0.f, 0.f, 0.f}, acc1 = {0.f, 0.f, 0.f, 0.f};
#pragma unroll
      for (int kc = 0; kc < 8; ++kc) {
        int lb = (kc * 2 + nt) * 512 + lane * 8;   // u16 index: chunk*8
        short8 bh = *(const short8*)&Bh[p][lb];
        short8 bl = *(const short8*)&Bl[p][lb];
        acc0 = __builtin_amdgcn_mfma_f32_16x16x32_bf16(qh[0][kc], bh, acc0, 0, 0, 0);
        acc0 = __builtin_amdgcn_mfma_f32_16x16x32_bf16(qh[0][kc], bl, acc0, 0, 0, 0);
        acc0 = __builtin_amdgcn_mfma_f32_16x16x32_bf16(ql[0][kc], bh, acc0, 0, 0, 0);
        acc1 = __builtin_amdgcn_mfma_f32_16x16x32_bf16(qh[1][kc], bh, acc1, 0, 0, 0);
        acc1 = __builtin_amdgcn_mfma_f32_16x16x32_bf16(qh[1][kc], bl, acc1, 0, 0, 0);
        acc1 = __builtin_amdgcn_mfma_f32_16x16x32_bf16(ql[1][kc], bh, acc1, 0, 0, 0);
      }
      uint32_t code = (uint32_t)(n0 + nt * 16 + lm);
      float csq = nt ? csq1 : csq0;
#pragma unroll
      for (int r = 0; r < 4; ++r) {
        float d0 = csq - 2.f * acc0[r];
        float d1 = csq - 2.f * acc1[r];
        unsigned long long k0 = ((unsigned long long)ord_f32(d0) << 32) | code;
        unsigned long long k1 = ((unsigned long long)ord_f32(d1) << 32) | code;
        if (k0 < rk[0][r]) rk[0][r] = k0;
        if (k1 < rk[1][r]) rk[1][r] = k1;
      }
    }
    if (pre) __syncthreads();   // drains DMA (vmcnt) + guards buffer reuse
  }

#pragma unroll
  for (int mt = 0; mt < 2; ++mt)
#pragma unroll
    for (int r = 0; r < 4; ++r) {
      unsigned long long k = rk[mt][r];
#pragma unroll
      for (int off = 1; off <= 8; off <<= 1) {
        uint32_t lo = (uint32_t)k, hi = (uint32_t)(k >> 32);
        uint32_t olo = __shfl_xor(lo, off, 64);
        uint32_t ohi = __shfl_xor(hi, off, 64);
        unsigned long long ok = ((unsigned long long)ohi << 32) | olo;
        if (ok < k) k = ok;
      }
      if (lm == 0) {
        int q = qw + mt * 16 + quad * 4 + r;
        if (q < nQ) atomicMin(&bkey[q], k);
      }
    }
}

// ---------------------------------------------------------------- gather + bicubic up -> split bf16 H
__global__ void k_upgather(const unsigned long long* __restrict__ bkey,
                           const float* __restrict__ cb,
                           u16* __restrict__ Hhi, u16* __restrict__ Hlo,
                           int sn, int tn, int last) {
  __shared__ int sidx[8][16];
  __shared__ float swgt[8][16];
  int tid = threadIdx.x;
  int p0 = blockIdx.x * 8;
  if (!last) {
    if (tid < 128) {
      int pp = tid >> 4, tap = tid & 15;
      int aa = tap >> 2, ee = tap & 3;
      int p = p0 + pp;
      int b = p >> 12, y = (p >> 8) & 15, x = p & 255;
      float cj = (y + 0.5f) * ((float)sn / 16.f) - 0.5f;
      float fj = floorf(cj); float tj = cj - fj; int ij = (int)fj;
      float wj = cubw(tj - (float)(aa - 1));
      int xj = min(max(ij + aa - 1, 0), sn - 1);
      float cl = (x + 0.5f) * ((float)tn / 256.f) - 0.5f;
      float fl = floorf(cl); float tl = cl - fl; int il = (int)fl;
      float wle = cubw(tl - (float)(ee - 1));
      int xl = min(max(il + ee - 1, 0), tn - 1);
      int n = (b * sn + xj) * tn + xl;
      sidx[pp][tap] = (int)((uint32_t)bkey[n] & (NBC - 1));
      swgt[pp][tap] = wj * wle;
    }
  } else {
    if (tid < 8) sidx[tid][0] = (int)((uint32_t)bkey[p0 + tid] & (NBC - 1));
  }
  __syncthreads();
  int c = tid;
  for (int pp = 0; pp < 8; ++pp) {
    float val;
    if (last) {
      val = cb[(size_t)sidx[pp][0] * 256 + c];
    } else {
      val = 0.f;
#pragma unroll
      for (int tap = 0; tap < 16; ++tap)
        val += swgt[pp][tap] * cb[(size_t)sidx[pp][tap] * 256 + c];
    }
    u16 h = bf16h(val);
    u16 l = bf16h(val - bf16f(h));
    size_t g = (size_t)(p0 + pp) * 256 + c;
    Hhi[g] = h;
    Hlo[g] = l;
  }
}

// ---------------------------------------------------------------- conv3x3 as split-bf16 MFMA implicit GEMM
__global__ __launch_bounds__(256) void k_conv(
    const u16* __restrict__ Hhi, const u16* __restrict__ Hlo,
    const u16* __restrict__ Wh, const u16* __restrict__ Wl,
    const float* __restrict__ bias, float* __restrict__ pm,
    float* __restrict__ lacc, int si) {
  __shared__ __align__(16) u16 Ah[128 * 40];
  __shared__ __align__(16) u16 Al[128 * 40];
  __shared__ __align__(16) u16 Bh[128 * 40];
  __shared__ __align__(16) u16 Bl[128 * 40];
  __shared__ float redl[4];
  int tid = threadIdx.x;
  int mt = blockIdx.x >> 1, nt = blockIdx.x & 1;
  int px0 = mt * 128;
  int b4096 = px0 & ~4095;
  int y = (px0 >> 8) & 15;
  int x0 = px0 & 255;
  int co0 = nt * 128;
  int wid = tid >> 6, lane = tid & 63;
  int wm = wid & 1, wn = wid >> 1;
  int lm = lane & 15, quad = lane >> 4, k0 = quad * 8;

  floatx4 acc[4][4];
#pragma unroll
  for (int i = 0; i < 4; ++i)
#pragma unroll
    for (int j = 0; j < 4; ++j) acc[i][j] = (floatx4){0.f, 0.f, 0.f, 0.f};

  for (int s = 0; s < 9; ++s) {
    int dy = s / 3 - 1, dx = s % 3 - 1;
    int ys = y + dy;
    if (ys < 0 || ys > 15) continue;       // wave-uniform skip
    const u16* wbh = Wh + (size_t)s * 65536;
    const u16* wbl = Wl + (size_t)s * 65536;
    for (int ci0 = 0; ci0 < 256; ci0 += 32) {
      __syncthreads();
#pragma unroll
      for (int it = 0; it < 2; ++it) {
        int slot = tid + it * 256;
        int pxl = slot >> 2, ch = (slot & 3) * 8;
        int xs = x0 + pxl + dx;
        uint4 vh = {0, 0, 0, 0}, vl = {0, 0, 0, 0};
        if (xs >= 0 && xs < 256) {
          size_t g = ((size_t)(b4096 + ys * 256 + xs)) * 256 + ci0 + ch;
          vh = *(const uint4*)(Hhi + g);
          vl = *(const uint4*)(Hlo + g);
        }
        *(uint4*)&Ah[pxl * 40 + ch] = vh;
        *(uint4*)&Al[pxl * 40 + ch] = vl;
        size_t gw = (size_t)(co0 + pxl) * 256 + ci0 + ch;
        *(uint4*)&Bh[pxl * 40 + ch] = *(const uint4*)(wbh + gw);
        *(uint4*)&Bl[pxl * 40 + ch] = *(const uint4*)(wbl + gw);
      }
      __syncthreads();
      short8 ah[4], al[4], bh[4], bl[4];
#pragma unroll
      for (int mi = 0; mi < 4; ++mi) {
        int r = wm * 64 + mi * 16 + lm;
        ah[mi] = *(const short8*)&Ah[r * 40 + k0];
        al[mi] = *(const short8*)&Al[r * 40 + k0];
      }
#pragma unroll
      for (int ni = 0; ni < 4; ++ni) {
        int r = wn * 64 + ni * 16 + lm;
        bh[ni] = *(const short8*)&Bh[r * 40 + k0];
        bl[ni] = *(const short8*)&Bl[r * 40 + k0];
      }
#pragma unroll
      for (int mi = 0; mi < 4; ++mi)
#pragma unroll
        for (int ni = 0; ni < 4; ++ni) {
          acc[mi][ni] = __builtin_amdgcn_mfma_f32_16x16x32_bf16(ah[mi], bh[ni], acc[mi][ni], 0, 0, 0);
          acc[mi][ni] = __builtin_amdgcn_mfma_f32_16x16x32_bf16(ah[mi], bl[ni], acc[mi][ni], 0, 0, 0);
          acc[mi][ni] = __builtin_amdgcn_mfma_f32_16x16x32_bf16(al[mi], bh[ni], acc[mi][ni], 0, 0, 0);
        }
    }
  }

  float lsum = 0.f;
#pragma unroll
  for (int mi = 0; mi < 4; ++mi) {
#pragma unroll
    for (int ni = 0; ni < 4; ++ni) {
      int co = co0 + wn * 64 + ni * 16 + lm;
      float bv = bias[co];
#pragma unroll
      for (int r = 0; r < 4; ++r) {
        int px = px0 + wm * 64 + mi * 16 + quad * 4 + r;
        size_t g = (size_t)px * 256 + co;
        float h = bf16f(Hhi[g]) + bf16f(Hlo[g]);
        float o = 0.5f * h + 0.5f * (acc[mi][ni][r] + bv);
        float fr = pm[g] - o;
        pm[g] = fr;
        lsum += fr * fr;
      }
    }
  }
  for (int off = 32; off; off >>= 1) lsum += __shfl_xor(lsum, off, 64);
  if (lane == 0) redl[wid] = lsum;
  __syncthreads();
  if (tid == 0) atomicAdd(&lacc[si], redl[0] + redl[1] + redl[2] + redl[3]);
}

// ---------------------------------------------------------------- histogram
__global__ void k_hist(const unsigned long long* __restrict__ bkey,
                       uint32_t* __restrict__ counts) {
  int i = blockIdx.x * 256 + threadIdx.x;
  if (i < NTOT) atomicAdd(&counts[(uint32_t)bkey[i] & (NBC - 1)], 1u);
}

// ---------------------------------------------------------------- loss + perplexity scalars
__global__ void k_scalars(const uint32_t* __restrict__ counts,
                          const float* __restrict__ lacc,
                          float* __restrict__ out) {
  __shared__ float red[4];
  int tid = threadIdx.x;
  float s = 0.f;
  for (int i = tid; i < NBC; i += 256) {
    float p = (float)counts[i] * (1.0f / (float)NTOT);
    s += p * logf(p + 1e-7f);
  }
  for (int off = 32; off; off >>= 1) s += __shfl_xor(s, off, 64);
  if ((tid & 63) == 0) red[tid >> 6] = s;
  __syncthreads();
  if (tid == 0) {
    float ent = red[0] + red[1] + red[2] + red[3];
    out[NEL + 1] = expf(-ent);
    float l = 0.f;
    for (int i = 0; i < 5; ++i) l += lacc[i];
    out[NEL] = l * (1.0f / (float)NEL / 5.0f);
  }
}

extern "C" void kernel_launch(void* const* d_in, const int* in_sizes, int n_in,
                              void* d_out, int out_size, void* d_ws, size_t ws_size,
                              hipStream_t stream) {
  const float* f  = (const float*)d_in[0];
  const float* cb = (const float*)d_in[1];
  const float* pw = (const float*)d_in[2];
  const float* pb = (const float*)d_in[3];
  float* out = (float*)d_out;

  char* ws = (char*)d_ws;
  size_t off = 0;
  auto alloc = [&](size_t bytes) {
    void* p = ws + off;
    off += (bytes + 255) & ~(size_t)255;
    return p;
  };
  float* pm    = (float*)alloc((size_t)NEL * 4);            // f_rest, pixel-major [p][c]
  u16*   Hhi   = (u16*)alloc((size_t)NEL * 2);
  u16*   Hlo   = (u16*)alloc((size_t)NEL * 2);
  float* rows  = (float*)alloc((size_t)8192 * 256 * 4);
  float* part  = (float*)alloc((size_t)8192 * 256 * 4);
  u16*   Whi   = (u16*)alloc((size_t)4 * 9 * 65536 * 2);
  u16*   Wlo   = (u16*)alloc((size_t)4 * 9 * 65536 * 2);
  u16*   CBfh  = (u16*)alloc((size_t)NBC * 256 * 2);        // fragment-major hi
  u16*   CBfl  = (u16*)alloc((size_t)NBC * 256 * 2);        // fragment-major lo
  float* cbsq  = (float*)alloc((size_t)NBC * 4);
  unsigned long long* bkey = (unsigned long long*)alloc((size_t)NTOT * 8);
  uint32_t* counts = (uint32_t*)alloc((size_t)NBC * 4);
  float* lacc = (float*)alloc(8 * 4);

  k_init<<<256, 256, 0, stream>>>(bkey, counts, lacc);
  k_f2pm<<<dim3(NPIX / 64, 4), 256, 0, stream>>>(f, pm);
  k_cbsq<<<NBC / 256, 256, 0, stream>>>(cb, cbsq);
  k_cbprep<<<1024, 256, 0, stream>>>(cb, CBfh, CBfl);
  k_wprep<<<4 * 9 * 256, 256, 0, stream>>>(pw, Whi, Wlo);

  const int SNs[5]   = {1, 2, 4, 8, 16};
  const int TNs[5]   = {4, 16, 64, 128, 256};
  const int PHI[5]   = {0, 1, 1, 2, 3};
  const int KCH[5]   = {256, 128, 32, 8, 2};  // code-chunk grid dim (256 tiles of 32)
  const int Ks[5]    = {16, 8, 2, 1, 1};
  int offs = 0;
  for (int si = 0; si < 5; ++si) {
    int sn = SNs[si], tn = TNs[si];
    int N = BB * sn * tn;
    int pj = JJ / sn, wl = LL / tn;
    unsigned long long* bk = bkey + offs;
    const float* qsrc;
    if (si < 4) {
      int K = Ks[si], npx = pj * wl;
      k_poolpart<<<dim3(N, K), 256, 0, stream>>>(pm, part, sn, tn, pj, wl, K, npx / K);
      k_poolfin<<<N, 256, 0, stream>>>(part, rows, K, 1.0f / (float)npx);
      qsrc = rows;
    } else {
      qsrc = pm;   // pixel-major residual IS the query matrix (fp32)
    }
    int qtiles = (N + MS_QB - 1) / MS_QB;
    int tpb = (NBC / 32) / KCH[si];
    dim3 g(qtiles, KCH[si]);
    k_msearch<<<g, 256, 0, stream>>>(qsrc, CBfh, CBfl, cbsq, bk, N, tpb);
    k_upgather<<<NPIX / 8, 256, 0, stream>>>(bk, cb, Hhi, Hlo, sn, tn, si == 4);
    k_conv<<<512, 256, 0, stream>>>(Hhi, Hlo,
                                    Whi + (size_t)PHI[si] * 9 * 65536,
                                    Wlo + (size_t)PHI[si] * 9 * 65536,
                                    pb + (size_t)PHI[si] * 256, pm, lacc, si);
    offs += N;
  }
  k_hist<<<(NTOT + 255) / 256, 256, 0, stream>>>(bkey, counts);
  k_out<<<dim3(NPIX / 64, 4), 256, 0, stream>>>(f, pm, out);
  k_scalars<<<1, 256, 0, stream>>>(counts, lacc, out);
}